// Round 1
// baseline (568.585 us; speedup 1.0000x reference)
//
#include <hip/hip_runtime.h>
#include <math.h>

#define BB 8
#define NN 4096
#define TT 8
#define HORQ 8
#define PD 128
#define HID 256
#define NHD 8
#define DH 32
#define FE 56
#define NC 8
#define CH 512

__device__ __forceinline__ float gelu_f(float x) {
    return 0.5f * x * (1.0f + erff(x * 0.70710678118654752440f));
}

// ---------------- fuse query_w into k/v projections ----------------
__global__ __launch_bounds__(256) void k_fuse(
    const float* __restrict__ qw, const float* __restrict__ qb,
    const float* __restrict__ ipw, const float* __restrict__ ipb,
    float* __restrict__ Wk, float* __restrict__ Wv,
    float* __restrict__ bk, float* __restrict__ bv)
{
    int j = threadIdx.x;
    int blk = blockIdx.x;
    if (blk < PD) {
        float sk = 0.f, sv = 0.f;
        for (int l = 0; l < HID; l++) {
            float w = qw[blk * HID + l];
            sk += w * ipw[l * 768 + 256 + j];
            sv += w * ipw[l * 768 + 512 + j];
        }
        Wk[blk * HID + j] = sk;
        Wv[blk * HID + j] = sv;
    } else {
        float sk = ipb[256 + j], sv = ipb[512 + j];
        for (int l = 0; l < HID; l++) {
            float w = qb[l];
            sk += w * ipw[l * 768 + 256 + j];
            sv += w * ipw[l * 768 + 512 + j];
        }
        bk[j] = sk;
        bv[j] = sv;
    }
}

// ---------------- encoder + all per-point projections (k,v,P1,P2) ----------------
// 16 points per block, 256 threads, weight-stationary accumulation.
__global__ __launch_bounds__(256) void k_enc(
    const float* __restrict__ obs, const int* __restrict__ vis,
    const float* __restrict__ rel,
    const float* __restrict__ lnw, const float* __restrict__ lnb,
    const float* __restrict__ w1, const float* __restrict__ b1,
    const float* __restrict__ w2, const float* __restrict__ b2,
    const float* __restrict__ Wk, const float* __restrict__ bk,
    const float* __restrict__ Wv, const float* __restrict__ bv,
    const float* __restrict__ rw1, const float* __restrict__ vw1,
    float* __restrict__ kb, float* __restrict__ vb,
    float* __restrict__ P1, float* __restrict__ P2)
{
    __shared__ float xn[16][FE];
    __shared__ float h1[16][PD];
    __shared__ float pt[16][PD];
    __shared__ float mu_s[16], rs_s[16];
    __shared__ float rxy[16][2];
    int tid = threadIdx.x;
    int bn0 = blockIdx.x * 16;

    // phase A: build feat
    for (int idx = tid; idx < 16 * FE; idx += 256) {
        int p = idx / FE, e = idx - p * FE;
        int t = e / 7, c = e - t * 7;
        int bn = bn0 + p;
        float v;
        if (c < 2)       v = obs[(bn * TT + t) * 2 + c];
        else if (c < 4)  v = (t == 0) ? 0.f : (obs[(bn * TT + t) * 2 + (c - 2)] - obs[(bn * TT + t - 1) * 2 + (c - 2)]);
        else if (c == 4) v = (float)vis[bn * TT + t];
        else             v = rel[bn * 2 + (c - 5)];
        xn[p][e] = v;
    }
    if (tid < 32) rxy[tid >> 1][tid & 1] = rel[(bn0 + (tid >> 1)) * 2 + (tid & 1)];
    __syncthreads();

    // phase B: LN stats (16 threads per point)
    {
        int g = tid >> 4, r = tid & 15;
        float s = 0.f, ss = 0.f;
        for (int e = r; e < FE; e += 16) { float v = xn[g][e]; s += v; ss += v * v; }
        #pragma unroll
        for (int m = 8; m; m >>= 1) { s += __shfl_xor(s, m, 16); ss += __shfl_xor(ss, m, 16); }
        if (r == 0) {
            float mu = s * (1.f / FE);
            float var = ss * (1.f / FE) - mu * mu;
            mu_s[g] = mu;
            rs_s[g] = rsqrtf(var + 1e-5f);
        }
    }
    __syncthreads();
    for (int idx = tid; idx < 16 * FE; idx += 256) {
        int p = idx / FE, e = idx - p * FE;
        xn[p][e] = (xn[p][e] - mu_s[p]) * rs_s[p] * lnw[e] + lnb[e];
    }
    __syncthreads();

    // phase D: h1 = gelu(x @ enc_w1 + b1)
    {
        int j = tid & 127, half = tid >> 7;
        float acc[8];
        float bj = b1[j];
        #pragma unroll
        for (int pp = 0; pp < 8; pp++) acc[pp] = bj;
        for (int i = 0; i < FE; i++) {
            float w = w1[i * PD + j];
            #pragma unroll
            for (int pp = 0; pp < 8; pp++) acc[pp] += xn[half * 8 + pp][i] * w;
        }
        #pragma unroll
        for (int pp = 0; pp < 8; pp++) h1[half * 8 + pp][j] = gelu_f(acc[pp]);
    }
    __syncthreads();

    // phase E: pt = gelu(h1 @ enc_w2 + b2)
    {
        int j = tid & 127, half = tid >> 7;
        float acc[8];
        float bj = b2[j];
        #pragma unroll
        for (int pp = 0; pp < 8; pp++) acc[pp] = bj;
        for (int i = 0; i < PD; i++) {
            float w = w2[i * PD + j];
            #pragma unroll
            for (int pp = 0; pp < 8; pp++) acc[pp] += h1[half * 8 + pp][i] * w;
        }
        #pragma unroll
        for (int pp = 0; pp < 8; pp++) pt[half * 8 + pp][j] = gelu_f(acc[pp]);
    }
    __syncthreads();

    // phase F: projections, weight-stationary
    {
        int j = tid;
        float acc[16];
        // K
        float bj = bk[j];
        #pragma unroll
        for (int p = 0; p < 16; p++) acc[p] = bj;
        for (int i = 0; i < PD; i++) {
            float w = Wk[i * HID + j];
            #pragma unroll
            for (int p = 0; p < 16; p++) acc[p] += pt[p][i] * w;
        }
        #pragma unroll
        for (int p = 0; p < 16; p++) kb[(size_t)(bn0 + p) * HID + j] = acc[p];
        // V
        bj = bv[j];
        #pragma unroll
        for (int p = 0; p < 16; p++) acc[p] = bj;
        for (int i = 0; i < PD; i++) {
            float w = Wv[i * HID + j];
            #pragma unroll
            for (int p = 0; p < 16; p++) acc[p] += pt[p][i] * w;
        }
        #pragma unroll
        for (int p = 0; p < 16; p++) vb[(size_t)(bn0 + p) * HID + j] = acc[p];
        // P1 = pt @ rh_w1[256:384] + rel @ rh_w1[384:386]
        float wr0 = rw1[384 * HID + j], wr1 = rw1[385 * HID + j];
        #pragma unroll
        for (int p = 0; p < 16; p++) acc[p] = rxy[p][0] * wr0 + rxy[p][1] * wr1;
        for (int i = 0; i < PD; i++) {
            float w = rw1[(256 + i) * HID + j];
            #pragma unroll
            for (int p = 0; p < 16; p++) acc[p] += pt[p][i] * w;
        }
        #pragma unroll
        for (int p = 0; p < 16; p++) P1[(size_t)(bn0 + p) * HID + j] = acc[p];
    }
    // P2 = pt @ vh_w1[256:384]  (width 128)
    {
        int j = tid & 127, half = tid >> 7;
        float acc[8];
        #pragma unroll
        for (int pp = 0; pp < 8; pp++) acc[pp] = 0.f;
        for (int i = 0; i < PD; i++) {
            float w = vw1[(256 + i) * PD + j];
            #pragma unroll
            for (int pp = 0; pp < 8; pp++) acc[pp] += pt[half * 8 + pp][i] * w;
        }
        #pragma unroll
        for (int pp = 0; pp < 8; pp++) P2[(size_t)(bn0 + half * 8 + pp) * PD + j] = acc[pp];
    }
}

// ---------------- tq and q ----------------
__global__ __launch_bounds__(256) void k_tq(
    const float* __restrict__ aobs, const float* __restrict__ avel,
    const float* __restrict__ te, const float* __restrict__ aw, const float* __restrict__ ab,
    const float* __restrict__ ipw, const float* __restrict__ ipb,
    float* __restrict__ qb_)
{
    __shared__ float af[32];
    __shared__ float tq[HID];
    int tid = threadIdx.x;
    int b = blockIdx.x >> 3, h = blockIdx.x & 7;
    if (tid < 32) {
        int t = tid >> 2, m = tid & 3;
        af[tid] = (m < 2) ? aobs[(b * TT + t) * 2 + m] : avel[(b * TT + t) * 2 + (m - 2)];
    }
    __syncthreads();
    float s = te[h * HID + tid] + ab[tid];
    for (int i = 0; i < 32; i++) s += af[i] * aw[i * HID + tid];
    tq[tid] = s;
    __syncthreads();
    float qv = ipb[tid];
    for (int i = 0; i < HID; i++) qv += tq[i] * ipw[i * 768 + tid];
    qb_[(size_t)blockIdx.x * HID + tid] = qv;
}

// ---------------- attention: partial (per b,head,chunk) ----------------
__global__ __launch_bounds__(256) void k_att(
    const float* __restrict__ qbuf, const float* __restrict__ kb, const float* __restrict__ vbuf,
    float* __restrict__ pm, float* __restrict__ pl, float* __restrict__ po)
{
    __shared__ float qs[8][DH];
    __shared__ float sc[8][CH];
    int tid = threadIdx.x;
    int bidx = blockIdx.x;
    int c = bidx & (NC - 1);
    int head = (bidx >> 3) & 7;
    int b = bidx >> 6;
    qs[tid >> 5][tid & 31] = qbuf[(size_t)(b * HORQ + (tid >> 5)) * HID + head * DH + (tid & 31)];
    __syncthreads();
    const float scale = 0.17677669529663688110f; // 1/sqrt(32)
    for (int nn = tid; nn < CH; nn += 256) {
        int n = c * CH + nn;
        const float* kp = kb + (size_t)(b * NN + n) * HID + head * DH;
        float kr[DH];
        #pragma unroll
        for (int u = 0; u < DH; u += 4) {
            float4 f = *reinterpret_cast<const float4*>(kp + u);
            kr[u] = f.x; kr[u + 1] = f.y; kr[u + 2] = f.z; kr[u + 3] = f.w;
        }
        #pragma unroll
        for (int qq = 0; qq < 8; qq++) {
            float s = 0.f;
            #pragma unroll
            for (int d = 0; d < DH; d++) s += qs[qq][d] * kr[d];
            sc[qq][nn] = s * scale;
        }
    }
    __syncthreads();
    int qq = tid >> 5, r = tid & 31;
    float mx = -1e30f;
    for (int nn = r; nn < CH; nn += 32) mx = fmaxf(mx, sc[qq][nn]);
    #pragma unroll
    for (int m = 16; m; m >>= 1) mx = fmaxf(mx, __shfl_xor(mx, m, 32));
    float sum = 0.f;
    for (int nn = r; nn < CH; nn += 32) { float e = expf(sc[qq][nn] - mx); sc[qq][nn] = e; sum += e; }
    #pragma unroll
    for (int m = 16; m; m >>= 1) sum += __shfl_xor(sum, m, 32);
    if (r == 0) { pm[bidx * 8 + qq] = mx; pl[bidx * 8 + qq] = sum; }
    __syncthreads();
    int d = tid & 31;
    const float* vp = vbuf + (size_t)(b * NN + c * CH) * HID + head * DH + d;
    float oa = 0.f;
    for (int nn = 0; nn < CH; nn++) oa += sc[qq][nn] * vp[(size_t)nn * HID];
    po[(size_t)(bidx * 8 + qq) * DH + d] = oa;
}

// ---------------- attention: combine chunks ----------------
__global__ __launch_bounds__(256) void k_attc(
    const float* __restrict__ pm, const float* __restrict__ pl, const float* __restrict__ po,
    float* __restrict__ ob)
{
    int tid = threadIdx.x;
    int bh = blockIdx.x; // b*8+head
    int b = bh >> 3, head = bh & 7;
    int qq = tid >> 5, d = tid & 31;
    float M = -1e30f;
    for (int c = 0; c < NC; c++) M = fmaxf(M, pm[(bh * NC + c) * 8 + qq]);
    float L = 0.f, o = 0.f;
    for (int c = 0; c < NC; c++) {
        float w = expf(pm[(bh * NC + c) * 8 + qq] - M);
        L += w * pl[(bh * NC + c) * 8 + qq];
        o += w * po[(size_t)((bh * NC + c) * 8 + qq) * DH + d];
    }
    ob[(size_t)(b * HORQ + qq) * HID + head * DH + d] = o / L;
}

// ---------------- future + all (b,h)-row heads ----------------
__global__ __launch_bounds__(256) void k_fut(
    const float* __restrict__ ob, const float* __restrict__ opw, const float* __restrict__ opb,
    const float* __restrict__ rw1, const float* __restrict__ rb1,
    const float* __restrict__ vw1, const float* __restrict__ vb1,
    const float* __restrict__ shw, const float* __restrict__ shb,
    const float* __restrict__ ahw, const float* __restrict__ ahb,
    float* __restrict__ F1, float* __restrict__ F2, float* __restrict__ dl, float* __restrict__ sem)
{
    __shared__ float orow[HID], fut[HID];
    int tid = threadIdx.x;
    int bh = blockIdx.x;
    orow[tid] = ob[(size_t)bh * HID + tid];
    __syncthreads();
    float s = opb[tid];
    for (int i = 0; i < HID; i++) s += orow[i] * opw[i * HID + tid];
    fut[tid] = s;
    __syncthreads();
    float f1 = rb1[tid];
    for (int i = 0; i < HID; i++) f1 += fut[i] * rw1[i * HID + tid];
    F1[(size_t)bh * HID + tid] = f1;
    if (tid < PD) {
        float f2 = vb1[tid];
        for (int i = 0; i < HID; i++) f2 += fut[i] * vw1[i * PD + tid];
        F2[(size_t)bh * PD + tid] = f2;
    }
    if (tid < 32) {
        float s3 = shb[tid];
        for (int i = 0; i < HID; i++) s3 += fut[i] * shw[i * 32 + tid];
        sem[bh * 32 + tid] = s3;
    }
    if (tid < 2) {
        float a = ahb[tid];
        for (int i = 0; i < HID; i++) a += fut[i] * ahw[i * 2 + tid];
        dl[bh * 2 + tid] = 0.1f * tanhf(a);
    }
}

// ---------------- anchor cumsum ----------------
__global__ void k_cum(const float* __restrict__ aobs, const float* __restrict__ dl, float* __restrict__ out0)
{
    int tid = threadIdx.x;
    if (tid < 16) {
        int b = tid >> 1, c = tid & 1;
        float acc = aobs[(b * TT + 7) * 2 + c];
        for (int h = 0; h < HORQ; h++) {
            acc += dl[(b * HORQ + h) * 2 + c];
            out0[(b * HORQ + h) * 2 + c] = acc;
        }
    }
}

// ---------------- final epilogue: pred_points + vis_logits ----------------
// one wave per point, loop h; lane l covers j = l, l+64, l+128, l+192
__global__ __launch_bounds__(256) void k_fin(
    const float* __restrict__ F1, const float* __restrict__ F2,
    const float* __restrict__ P1, const float* __restrict__ P2,
    const float* __restrict__ rw2, const float* __restrict__ rb2,
    const float* __restrict__ vw2, const float* __restrict__ vb2,
    const float* __restrict__ ap,
    float* __restrict__ out1, float* __restrict__ out2)
{
    int tid = threadIdx.x;
    int w = tid >> 6, l = tid & 63;
    size_t bn = (size_t)blockIdx.x * 4 + w;
    int b = (int)(bn >> 12);
    float p1r[4], w20[4], w21[4];
    #pragma unroll
    for (int u = 0; u < 4; u++) {
        int j = l + 64 * u;
        p1r[u] = P1[bn * HID + j];
        w20[u] = rw2[j * 2];
        w21[u] = rw2[j * 2 + 1];
    }
    float p2r[2], wv2r[2];
    #pragma unroll
    for (int u = 0; u < 2; u++) {
        int j = l + 64 * u;
        p2r[u] = P2[bn * PD + j];
        wv2r[u] = vw2[j];
    }
    float rb20 = rb2[0], rb21 = rb2[1], vb20 = vb2[0];
    for (int h = 0; h < HORQ; h++) {
        const float* f1p = F1 + (size_t)(b * HORQ + h) * HID;
        const float* f2p = F2 + (size_t)(b * HORQ + h) * PD;
        float s0 = 0.f, s1 = 0.f, sv = 0.f;
        #pragma unroll
        for (int u = 0; u < 4; u++) {
            float g = gelu_f(f1p[l + 64 * u] + p1r[u]);
            s0 += g * w20[u];
            s1 += g * w21[u];
        }
        #pragma unroll
        for (int u = 0; u < 2; u++) {
            float g = gelu_f(f2p[l + 64 * u] + p2r[u]);
            sv += g * wv2r[u];
        }
        #pragma unroll
        for (int m = 32; m; m >>= 1) {
            s0 += __shfl_xor(s0, m);
            s1 += __shfl_xor(s1, m);
            sv += __shfl_xor(sv, m);
        }
        if (l == 0) {
            float rx = 0.1f * tanhf(s0 + rb20);
            float ry = 0.1f * tanhf(s1 + rb21);
            out1[(bn * HORQ + h) * 2 + 0] = ap[(b * HORQ + h) * 2 + 0] + rx;
            out1[(bn * HORQ + h) * 2 + 1] = ap[(b * HORQ + h) * 2 + 1] + ry;
            out2[bn * HORQ + h] = sv + vb20;
        }
    }
}

extern "C" void kernel_launch(void* const* d_in, const int* in_sizes, int n_in,
                              void* d_out, int out_size, void* d_ws, size_t ws_size,
                              hipStream_t stream)
{
    const float* obs  = (const float*)d_in[0];
    const int*   vis  = (const int*)d_in[1];
    const float* rel  = (const float*)d_in[2];
    const float* aobs = (const float*)d_in[3];
    const float* avel = (const float*)d_in[4];
    // d_in[5] semantic_feat unused
    const float* lnw = (const float*)d_in[6];
    const float* lnb = (const float*)d_in[7];
    const float* ew1 = (const float*)d_in[8];
    const float* eb1 = (const float*)d_in[9];
    const float* ew2 = (const float*)d_in[10];
    const float* eb2 = (const float*)d_in[11];
    const float* te  = (const float*)d_in[12];
    const float* aw  = (const float*)d_in[13];
    const float* ab  = (const float*)d_in[14];
    const float* qw  = (const float*)d_in[15];
    const float* qbias = (const float*)d_in[16];
    const float* ipw = (const float*)d_in[17];
    const float* ipb = (const float*)d_in[18];
    const float* opw = (const float*)d_in[19];
    const float* opb = (const float*)d_in[20];
    const float* ahw = (const float*)d_in[21];
    const float* ahb = (const float*)d_in[22];
    const float* rw1 = (const float*)d_in[23];
    const float* rb1 = (const float*)d_in[24];
    const float* rw2 = (const float*)d_in[25];
    const float* rb2 = (const float*)d_in[26];
    const float* vw1 = (const float*)d_in[27];
    const float* vb1 = (const float*)d_in[28];
    const float* vw2 = (const float*)d_in[29];
    const float* vb2 = (const float*)d_in[30];
    const float* shw = (const float*)d_in[31];
    const float* shb = (const float*)d_in[32];

    float* W = (float*)d_ws;
    size_t o = 0;
    float* Wk  = W + o; o += (size_t)PD * HID;
    float* Wv  = W + o; o += (size_t)PD * HID;
    float* bk  = W + o; o += HID;
    float* bv  = W + o; o += HID;
    float* qb_ = W + o; o += (size_t)BB * HORQ * HID;
    float* F1  = W + o; o += (size_t)BB * HORQ * HID;
    float* F2  = W + o; o += (size_t)BB * HORQ * PD;
    float* dl  = W + o; o += (size_t)BB * HORQ * 2;
    float* ob  = W + o; o += (size_t)BB * HORQ * HID;
    float* pm  = W + o; o += 512 * 8;
    float* pl  = W + o; o += 512 * 8;
    float* po  = W + o; o += (size_t)512 * 8 * DH;
    float* kb  = W + o; o += (size_t)BB * NN * HID;
    float* vbuf= W + o; o += (size_t)BB * NN * HID;
    float* P1  = W + o; o += (size_t)BB * NN * HID;
    float* P2  = W + o; o += (size_t)BB * NN * PD;

    float* out0 = (float*)d_out;
    float* out1 = out0 + BB * HORQ * 2;
    float* out2 = out1 + (size_t)BB * NN * HORQ * 2;
    float* out3 = out2 + (size_t)BB * NN * HORQ;

    k_fuse<<<PD + 1, 256, 0, stream>>>(qw, qbias, ipw, ipb, Wk, Wv, bk, bv);
    k_enc<<<BB * NN / 16, 256, 0, stream>>>(obs, vis, rel, lnw, lnb, ew1, eb1, ew2, eb2,
                                            Wk, bk, Wv, bv, rw1, vw1, kb, vbuf, P1, P2);
    k_tq<<<BB * HORQ, 256, 0, stream>>>(aobs, avel, te, aw, ab, ipw, ipb, qb_);
    k_att<<<BB * NHD * NC, 256, 0, stream>>>(qb_, kb, vbuf, pm, pl, po);
    k_attc<<<BB * NHD, 256, 0, stream>>>(pm, pl, po, ob);
    k_fut<<<BB * HORQ, 256, 0, stream>>>(ob, opw, opb, rw1, rb1, vw1, vb1, shw, shb, ahw, ahb,
                                         F1, F2, dl, out3);
    k_cum<<<1, 64, 0, stream>>>(aobs, dl, out0);
    k_fin<<<BB * NN / 4, 256, 0, stream>>>(F1, F2, P1, P2, rw2, rb2, vw2, vb2, out0, out1, out2);
}

// Round 2
// 350.150 us; speedup vs baseline: 1.6238x; 1.6238x over previous
//
#include <hip/hip_runtime.h>
#include <math.h>

#define BB 8
#define NN 4096
#define TT 8
#define HORQ 8
#define PD 128
#define HID 256
#define NHD 8
#define DH 32
#define FE 56
#define NC 8
#define CH 512

typedef __attribute__((ext_vector_type(8))) short short8;
typedef __attribute__((ext_vector_type(4))) float floatx4;

__device__ __forceinline__ float gelu_f(float x) {
    return 0.5f * x * (1.0f + erff(x * 0.70710678118654752440f));
}

// fp32 -> bf16 round-to-nearest-even
__device__ __forceinline__ short f2b(float x) {
    union { float f; unsigned u; } c; c.f = x;
    unsigned r = c.u + 0x7fffu + ((c.u >> 16) & 1u);
    return (short)(r >> 16);
}

// ---------------- fuse query_w into k/v projections (fp32) ----------------
__global__ __launch_bounds__(256) void k_fuse(
    const float* __restrict__ qw, const float* __restrict__ qb,
    const float* __restrict__ ipw, const float* __restrict__ ipb,
    float* __restrict__ Wk, float* __restrict__ Wv,
    float* __restrict__ bk, float* __restrict__ bv)
{
    int j = threadIdx.x;
    int blk = blockIdx.x;
    if (blk < PD) {
        float sk = 0.f, sv = 0.f;
        for (int l = 0; l < HID; l++) {
            float w = qw[blk * HID + l];
            sk += w * ipw[l * 768 + 256 + j];
            sv += w * ipw[l * 768 + 512 + j];
        }
        Wk[blk * HID + j] = sk;
        Wv[blk * HID + j] = sv;
    } else {
        float sk = ipb[256 + j], sv = ipb[512 + j];
        for (int l = 0; l < HID; l++) {
            float w = qb[l];
            sk += w * ipw[l * 768 + 256 + j];
            sv += w * ipw[l * 768 + 512 + j];
        }
        bk[j] = sk;
        bv[j] = sv;
    }
}

// ---------------- pack weights into bf16 MFMA B-fragment layout ----------------
// B-frag layout for mfma_f32_16x16x32_bf16: lane holds B[k=quad*8+j][n=lane&15].
// Wfrag[nt][ks][lane][j], nt in [0,56): n = nt*16+(lane&15), k = ks*32+quad*8+j.
// Fused big-W columns: 0..255 Wk | 256..511 Wv | 512..767 rh_w1[256+k] | 768..895 vh_w1[256+k]
__global__ __launch_bounds__(256) void k_prep(
    const float* __restrict__ Wk, const float* __restrict__ Wv,
    const float* __restrict__ rw1, const float* __restrict__ vw1,
    const float* __restrict__ w1, const float* __restrict__ w2,
    short* __restrict__ Wfrag, short* __restrict__ w1frag, short* __restrict__ w2frag)
{
    int tid = threadIdx.x;
    int blk = blockIdx.x;
    int ks = tid >> 6, lane = tid & 63;
    int quad = lane >> 4, c16 = lane & 15;
    if (blk < 56) {
        int nt = blk;
        int n = nt * 16 + c16;
        for (int j = 0; j < 8; j++) {
            int k = ks * 32 + quad * 8 + j;
            float v;
            if (n < 256)      v = Wk[k * HID + n];
            else if (n < 512) v = Wv[k * HID + (n - 256)];
            else if (n < 768) v = rw1[(256 + k) * HID + (n - 512)];
            else              v = vw1[(256 + k) * PD + (n - 768)];
            Wfrag[((nt * 4 + ks) * 64 + lane) * 8 + j] = f2b(v);
        }
    } else if (blk < 64) {
        if (ks < 2) {
            int nt = blk - 56;
            int n = nt * 16 + c16;
            for (int j = 0; j < 8; j++) {
                int k = ks * 32 + quad * 8 + j;
                float v = (k < FE) ? w1[k * PD + n] : 0.f;
                w1frag[((nt * 2 + ks) * 64 + lane) * 8 + j] = f2b(v);
            }
        }
    } else {
        int nt = blk - 64;
        int n = nt * 16 + c16;
        for (int j = 0; j < 8; j++) {
            int k = ks * 32 + quad * 8 + j;
            w2frag[((nt * 4 + ks) * 64 + lane) * 8 + j] = f2b(w2[k * PD + n]);
        }
    }
}

// ---------------- fused encoder + projections via bf16 MFMA ----------------
// 64 points/block, 256 threads (4 waves).
// LDS: u1 (xnf fp32 64x57  UNION  h1b bf16 64x136) | xnb bf16 64x72 | ptb bf16 64x136 | rxy | mu | rs
#define U1_OFF 0
#define XNB_OFF 17408
#define PTB_OFF 26624
#define RXY_OFF 44032
#define MU_OFF 44544
#define RS_OFF 44800
#define SMEM_BYTES 45056

__global__ __launch_bounds__(256) void k_main(
    const float* __restrict__ obs, const int* __restrict__ vis,
    const float* __restrict__ rel,
    const float* __restrict__ lnw, const float* __restrict__ lnb,
    const float* __restrict__ b1, const float* __restrict__ b2,
    const short* __restrict__ Wfrag, const short* __restrict__ w1frag,
    const short* __restrict__ w2frag,
    const float* __restrict__ bk, const float* __restrict__ bv,
    const float* __restrict__ rw1,
    float* __restrict__ kb, float* __restrict__ vb,
    float* __restrict__ P1, float* __restrict__ P2)
{
    __shared__ __align__(16) char smem[SMEM_BYTES];
    float* xnf = (float*)(smem + U1_OFF);       // [64][57]
    short* h1b = (short*)(smem + U1_OFF);       // [64][136]
    short* xnb = (short*)(smem + XNB_OFF);      // [64][72]
    short* ptb = (short*)(smem + PTB_OFF);      // [64][136]
    float* rxyS = (float*)(smem + RXY_OFF);     // [64][2]
    float* muS = (float*)(smem + MU_OFF);       // [64]
    float* rsS = (float*)(smem + RS_OFF);       // [64]

    int tid = threadIdx.x;
    int w = tid >> 6, lane = tid & 63;
    int quad = lane >> 4, c16 = lane & 15;
    int bn0 = blockIdx.x * 64;

    // phase A: build feat (fp32)
    for (int idx = tid; idx < 64 * FE; idx += 256) {
        int p = idx / FE, e = idx - p * FE;
        int t = e / 7, c = e - t * 7;
        int bn = bn0 + p;
        float v;
        if (c < 2)       v = obs[(bn * TT + t) * 2 + c];
        else if (c < 4)  v = (t == 0) ? 0.f : (obs[(bn * TT + t) * 2 + (c - 2)] - obs[(bn * TT + t - 1) * 2 + (c - 2)]);
        else if (c == 4) v = (float)vis[bn * TT + t];
        else             v = rel[bn * 2 + (c - 5)];
        xnf[p * 57 + e] = v;
    }
    if (tid < 128) rxyS[tid] = rel[bn0 * 2 + tid];
    __syncthreads();

    // phase B: LN stats, one thread per point
    if (tid < 64) {
        float s = 0.f, ss = 0.f;
        for (int e = 0; e < FE; e++) { float v = xnf[tid * 57 + e]; s += v; ss += v * v; }
        float mu = s * (1.f / FE);
        float var = ss * (1.f / FE) - mu * mu;
        muS[tid] = mu;
        rsS[tid] = rsqrtf(var + 1e-5f);
    }
    __syncthreads();

    // phase C: normalize -> bf16 A-layout (rows padded to 72, cols 56..63 zero)
    for (int idx = tid; idx < 64 * 64; idx += 256) {
        int p = idx >> 6, e = idx & 63;
        float v = 0.f;
        if (e < FE) v = (xnf[p * 57 + e] - muS[p]) * rsS[p] * lnw[e] + lnb[e];
        xnb[p * 72 + e] = f2b(v);
    }
    __syncthreads();

    // phase D: enc1 = gelu(X[64x64] @ w1[64x128]) -> h1b
    {
        short8 af1[4][2];
        #pragma unroll
        for (int mt = 0; mt < 4; mt++)
            #pragma unroll
            for (int ks = 0; ks < 2; ks++)
                af1[mt][ks] = *(const short8*)(xnb + (mt * 16 + c16) * 72 + ks * 32 + quad * 8);
        #pragma unroll
        for (int ntl = 0; ntl < 2; ntl++) {
            int nt = w * 2 + ntl;
            short8 bf1[2];
            #pragma unroll
            for (int ks = 0; ks < 2; ks++)
                bf1[ks] = *(const short8*)(w1frag + ((nt * 2 + ks) * 64 + lane) * 8);
            int col = nt * 16 + c16;
            float bb = b1[col];
            #pragma unroll
            for (int mt = 0; mt < 4; mt++) {
                floatx4 acc = {0.f, 0.f, 0.f, 0.f};
                acc = __builtin_amdgcn_mfma_f32_16x16x32_bf16(af1[mt][0], bf1[0], acc, 0, 0, 0);
                acc = __builtin_amdgcn_mfma_f32_16x16x32_bf16(af1[mt][1], bf1[1], acc, 0, 0, 0);
                #pragma unroll
                for (int r = 0; r < 4; r++) {
                    int row = mt * 16 + quad * 4 + r;
                    h1b[row * 136 + col] = f2b(gelu_f(acc[r] + bb));
                }
            }
        }
    }
    __syncthreads();

    // phase E: enc2 = gelu(h1[64x128] @ w2[128x128]) -> ptb
    {
        short8 af2[4][4];
        #pragma unroll
        for (int mt = 0; mt < 4; mt++)
            #pragma unroll
            for (int ks = 0; ks < 4; ks++)
                af2[mt][ks] = *(const short8*)(h1b + (mt * 16 + c16) * 136 + ks * 32 + quad * 8);
        #pragma unroll
        for (int ntl = 0; ntl < 2; ntl++) {
            int nt = w * 2 + ntl;
            short8 bf2[4];
            #pragma unroll
            for (int ks = 0; ks < 4; ks++)
                bf2[ks] = *(const short8*)(w2frag + ((nt * 4 + ks) * 64 + lane) * 8);
            int col = nt * 16 + c16;
            float bb = b2[col];
            #pragma unroll
            for (int mt = 0; mt < 4; mt++) {
                floatx4 acc = {0.f, 0.f, 0.f, 0.f};
                #pragma unroll
                for (int ks = 0; ks < 4; ks++)
                    acc = __builtin_amdgcn_mfma_f32_16x16x32_bf16(af2[mt][ks], bf2[ks], acc, 0, 0, 0);
                #pragma unroll
                for (int r = 0; r < 4; r++) {
                    int row = mt * 16 + quad * 4 + r;
                    ptb[row * 136 + col] = f2b(gelu_f(acc[r] + bb));
                }
            }
        }
    }
    __syncthreads();

    // phase F: big GEMM [64x128] @ [128x896] -> kb/vb/P1/P2
    {
        short8 af[4][4];
        #pragma unroll
        for (int mt = 0; mt < 4; mt++)
            #pragma unroll
            for (int ks = 0; ks < 4; ks++)
                af[mt][ks] = *(const short8*)(ptb + (mt * 16 + c16) * 136 + ks * 32 + quad * 8);
        for (int i = 0; i < 14; i++) {
            int nt = w + i * 4;
            short8 bf[4];
            #pragma unroll
            for (int ks = 0; ks < 4; ks++)
                bf[ks] = *(const short8*)(Wfrag + ((nt * 4 + ks) * 64 + lane) * 8);
            floatx4 acc[4];
            #pragma unroll
            for (int mt = 0; mt < 4; mt++) {
                acc[mt] = (floatx4){0.f, 0.f, 0.f, 0.f};
                #pragma unroll
                for (int ks = 0; ks < 4; ks++)
                    acc[mt] = __builtin_amdgcn_mfma_f32_16x16x32_bf16(af[mt][ks], bf[ks], acc[mt], 0, 0, 0);
            }
            int n = nt * 16 + c16;
            if (nt < 16) {
                float bb = bk[n];
                #pragma unroll
                for (int mt = 0; mt < 4; mt++)
                    #pragma unroll
                    for (int r = 0; r < 4; r++) {
                        int row = mt * 16 + quad * 4 + r;
                        kb[(size_t)(bn0 + row) * HID + n] = acc[mt][r] + bb;
                    }
            } else if (nt < 32) {
                int j = n - 256;
                float bb = bv[j];
                #pragma unroll
                for (int mt = 0; mt < 4; mt++)
                    #pragma unroll
                    for (int r = 0; r < 4; r++) {
                        int row = mt * 16 + quad * 4 + r;
                        vb[(size_t)(bn0 + row) * HID + j] = acc[mt][r] + bb;
                    }
            } else if (nt < 48) {
                int j = n - 512;
                float wr0 = rw1[384 * HID + j], wr1 = rw1[385 * HID + j];
                #pragma unroll
                for (int mt = 0; mt < 4; mt++)
                    #pragma unroll
                    for (int r = 0; r < 4; r++) {
                        int row = mt * 16 + quad * 4 + r;
                        P1[(size_t)(bn0 + row) * HID + j] =
                            acc[mt][r] + rxyS[row * 2] * wr0 + rxyS[row * 2 + 1] * wr1;
                    }
            } else {
                int j = n - 768;
                #pragma unroll
                for (int mt = 0; mt < 4; mt++)
                    #pragma unroll
                    for (int r = 0; r < 4; r++) {
                        int row = mt * 16 + quad * 4 + r;
                        P2[(size_t)(bn0 + row) * PD + j] = acc[mt][r];
                    }
            }
        }
    }
}

// ---------------- tq and q ----------------
__global__ __launch_bounds__(256) void k_tq(
    const float* __restrict__ aobs, const float* __restrict__ avel,
    const float* __restrict__ te, const float* __restrict__ aw, const float* __restrict__ ab,
    const float* __restrict__ ipw, const float* __restrict__ ipb,
    float* __restrict__ qb_)
{
    __shared__ float af[32];
    __shared__ float tq[HID];
    int tid = threadIdx.x;
    int b = blockIdx.x >> 3, h = blockIdx.x & 7;
    if (tid < 32) {
        int t = tid >> 2, m = tid & 3;
        af[tid] = (m < 2) ? aobs[(b * TT + t) * 2 + m] : avel[(b * TT + t) * 2 + (m - 2)];
    }
    __syncthreads();
    float s = te[h * HID + tid] + ab[tid];
    for (int i = 0; i < 32; i++) s += af[i] * aw[i * HID + tid];
    tq[tid] = s;
    __syncthreads();
    float qv = ipb[tid];
    for (int i = 0; i < HID; i++) qv += tq[i] * ipw[i * 768 + tid];
    qb_[(size_t)blockIdx.x * HID + tid] = qv;
}

// ---------------- attention: partial (per b,head,chunk) ----------------
__global__ __launch_bounds__(256) void k_att(
    const float* __restrict__ qbuf, const float* __restrict__ kb, const float* __restrict__ vbuf,
    float* __restrict__ pm, float* __restrict__ pl, float* __restrict__ po)
{
    __shared__ float qs[8][DH];
    __shared__ float sc[8][CH];
    int tid = threadIdx.x;
    int bidx = blockIdx.x;
    int c = bidx & (NC - 1);
    int head = (bidx >> 3) & 7;
    int b = bidx >> 6;
    qs[tid >> 5][tid & 31] = qbuf[(size_t)(b * HORQ + (tid >> 5)) * HID + head * DH + (tid & 31)];
    __syncthreads();
    const float scale = 0.17677669529663688110f; // 1/sqrt(32)
    for (int nn = tid; nn < CH; nn += 256) {
        int n = c * CH + nn;
        const float* kp = kb + (size_t)(b * NN + n) * HID + head * DH;
        float kr[DH];
        #pragma unroll
        for (int u = 0; u < DH; u += 4) {
            float4 f = *reinterpret_cast<const float4*>(kp + u);
            kr[u] = f.x; kr[u + 1] = f.y; kr[u + 2] = f.z; kr[u + 3] = f.w;
        }
        #pragma unroll
        for (int qq = 0; qq < 8; qq++) {
            float s = 0.f;
            #pragma unroll
            for (int d = 0; d < DH; d++) s += qs[qq][d] * kr[d];
            sc[qq][nn] = s * scale;
        }
    }
    __syncthreads();
    int qq = tid >> 5, r = tid & 31;
    float mx = -1e30f;
    for (int nn = r; nn < CH; nn += 32) mx = fmaxf(mx, sc[qq][nn]);
    #pragma unroll
    for (int m = 16; m; m >>= 1) mx = fmaxf(mx, __shfl_xor(mx, m, 32));
    float sum = 0.f;
    for (int nn = r; nn < CH; nn += 32) { float e = expf(sc[qq][nn] - mx); sc[qq][nn] = e; sum += e; }
    #pragma unroll
    for (int m = 16; m; m >>= 1) sum += __shfl_xor(sum, m, 32);
    if (r == 0) { pm[bidx * 8 + qq] = mx; pl[bidx * 8 + qq] = sum; }
    __syncthreads();
    int d = tid & 31;
    const float* vp = vbuf + (size_t)(b * NN + c * CH) * HID + head * DH + d;
    float oa = 0.f;
    for (int nn = 0; nn < CH; nn++) oa += sc[qq][nn] * vp[(size_t)nn * HID];
    po[(size_t)(bidx * 8 + qq) * DH + d] = oa;
}

// ---------------- attention: combine chunks ----------------
__global__ __launch_bounds__(256) void k_attc(
    const float* __restrict__ pm, const float* __restrict__ pl, const float* __restrict__ po,
    float* __restrict__ ob)
{
    int tid = threadIdx.x;
    int bh = blockIdx.x; // b*8+head
    int b = bh >> 3, head = bh & 7;
    int qq = tid >> 5, d = tid & 31;
    float M = -1e30f;
    for (int c = 0; c < NC; c++) M = fmaxf(M, pm[(bh * NC + c) * 8 + qq]);
    float L = 0.f, o = 0.f;
    for (int c = 0; c < NC; c++) {
        float w = expf(pm[(bh * NC + c) * 8 + qq] - M);
        L += w * pl[(bh * NC + c) * 8 + qq];
        o += w * po[(size_t)((bh * NC + c) * 8 + qq) * DH + d];
    }
    ob[(size_t)(b * HORQ + qq) * HID + head * DH + d] = o / L;
}

// ---------------- future + all (b,h)-row heads ----------------
__global__ __launch_bounds__(256) void k_fut(
    const float* __restrict__ ob, const float* __restrict__ opw, const float* __restrict__ opb,
    const float* __restrict__ rw1, const float* __restrict__ rb1,
    const float* __restrict__ vw1, const float* __restrict__ vb1,
    const float* __restrict__ shw, const float* __restrict__ shb,
    const float* __restrict__ ahw, const float* __restrict__ ahb,
    float* __restrict__ F1, float* __restrict__ F2, float* __restrict__ dl, float* __restrict__ sem)
{
    __shared__ float orow[HID], fut[HID];
    int tid = threadIdx.x;
    int bh = blockIdx.x;
    orow[tid] = ob[(size_t)bh * HID + tid];
    __syncthreads();
    float s = opb[tid];
    for (int i = 0; i < HID; i++) s += orow[i] * opw[i * HID + tid];
    fut[tid] = s;
    __syncthreads();
    float f1 = rb1[tid];
    for (int i = 0; i < HID; i++) f1 += fut[i] * rw1[i * HID + tid];
    F1[(size_t)bh * HID + tid] = f1;
    if (tid < PD) {
        float f2 = vb1[tid];
        for (int i = 0; i < HID; i++) f2 += fut[i] * vw1[i * PD + tid];
        F2[(size_t)bh * PD + tid] = f2;
    }
    if (tid < 32) {
        float s3 = shb[tid];
        for (int i = 0; i < HID; i++) s3 += fut[i] * shw[i * 32 + tid];
        sem[bh * 32 + tid] = s3;
    }
    if (tid < 2) {
        float a = ahb[tid];
        for (int i = 0; i < HID; i++) a += fut[i] * ahw[i * 2 + tid];
        dl[bh * 2 + tid] = 0.1f * tanhf(a);
    }
}

// ---------------- anchor cumsum ----------------
__global__ void k_cum(const float* __restrict__ aobs, const float* __restrict__ dl, float* __restrict__ out0)
{
    int tid = threadIdx.x;
    if (tid < 16) {
        int b = tid >> 1, c = tid & 1;
        float acc = aobs[(b * TT + 7) * 2 + c];
        for (int h = 0; h < HORQ; h++) {
            acc += dl[(b * HORQ + h) * 2 + c];
            out0[(b * HORQ + h) * 2 + c] = acc;
        }
    }
}

// ---------------- final epilogue: pred_points + vis_logits ----------------
__global__ __launch_bounds__(256) void k_fin(
    const float* __restrict__ F1, const float* __restrict__ F2,
    const float* __restrict__ P1, const float* __restrict__ P2,
    const float* __restrict__ rw2, const float* __restrict__ rb2,
    const float* __restrict__ vw2, const float* __restrict__ vb2,
    const float* __restrict__ ap,
    float* __restrict__ out1, float* __restrict__ out2)
{
    int tid = threadIdx.x;
    int w = tid >> 6, l = tid & 63;
    size_t bn = (size_t)blockIdx.x * 4 + w;
    int b = (int)(bn >> 12);
    float p1r[4], w20[4], w21[4];
    #pragma unroll
    for (int u = 0; u < 4; u++) {
        int j = l + 64 * u;
        p1r[u] = P1[bn * HID + j];
        w20[u] = rw2[j * 2];
        w21[u] = rw2[j * 2 + 1];
    }
    float p2r[2], wv2r[2];
    #pragma unroll
    for (int u = 0; u < 2; u++) {
        int j = l + 64 * u;
        p2r[u] = P2[bn * PD + j];
        wv2r[u] = vw2[j];
    }
    float rb20 = rb2[0], rb21 = rb2[1], vb20 = vb2[0];
    for (int h = 0; h < HORQ; h++) {
        const float* f1p = F1 + (size_t)(b * HORQ + h) * HID;
        const float* f2p = F2 + (size_t)(b * HORQ + h) * PD;
        float s0 = 0.f, s1 = 0.f, sv = 0.f;
        #pragma unroll
        for (int u = 0; u < 4; u++) {
            float g = gelu_f(f1p[l + 64 * u] + p1r[u]);
            s0 += g * w20[u];
            s1 += g * w21[u];
        }
        #pragma unroll
        for (int u = 0; u < 2; u++) {
            float g = gelu_f(f2p[l + 64 * u] + p2r[u]);
            sv += g * wv2r[u];
        }
        #pragma unroll
        for (int m = 32; m; m >>= 1) {
            s0 += __shfl_xor(s0, m);
            s1 += __shfl_xor(s1, m);
            sv += __shfl_xor(sv, m);
        }
        if (l == 0) {
            float rx = 0.1f * tanhf(s0 + rb20);
            float ry = 0.1f * tanhf(s1 + rb21);
            out1[(bn * HORQ + h) * 2 + 0] = ap[(b * HORQ + h) * 2 + 0] + rx;
            out1[(bn * HORQ + h) * 2 + 1] = ap[(b * HORQ + h) * 2 + 1] + ry;
            out2[bn * HORQ + h] = sv + vb20;
        }
    }
}

extern "C" void kernel_launch(void* const* d_in, const int* in_sizes, int n_in,
                              void* d_out, int out_size, void* d_ws, size_t ws_size,
                              hipStream_t stream)
{
    const float* obs  = (const float*)d_in[0];
    const int*   vis  = (const int*)d_in[1];
    const float* rel  = (const float*)d_in[2];
    const float* aobs = (const float*)d_in[3];
    const float* avel = (const float*)d_in[4];
    const float* lnw = (const float*)d_in[6];
    const float* lnb = (const float*)d_in[7];
    const float* ew1 = (const float*)d_in[8];
    const float* eb1 = (const float*)d_in[9];
    const float* ew2 = (const float*)d_in[10];
    const float* eb2 = (const float*)d_in[11];
    const float* te  = (const float*)d_in[12];
    const float* aw  = (const float*)d_in[13];
    const float* ab  = (const float*)d_in[14];
    const float* qw  = (const float*)d_in[15];
    const float* qbias = (const float*)d_in[16];
    const float* ipw = (const float*)d_in[17];
    const float* ipb = (const float*)d_in[18];
    const float* opw = (const float*)d_in[19];
    const float* opb = (const float*)d_in[20];
    const float* ahw = (const float*)d_in[21];
    const float* ahb = (const float*)d_in[22];
    const float* rw1 = (const float*)d_in[23];
    const float* rb1 = (const float*)d_in[24];
    const float* rw2 = (const float*)d_in[25];
    const float* rb2 = (const float*)d_in[26];
    const float* vw1 = (const float*)d_in[27];
    const float* vb1 = (const float*)d_in[28];
    const float* vw2 = (const float*)d_in[29];
    const float* vb2 = (const float*)d_in[30];
    const float* shw = (const float*)d_in[31];
    const float* shb = (const float*)d_in[32];

    float* W = (float*)d_ws;
    size_t o = 0;
    float* Wk  = W + o; o += (size_t)PD * HID;
    float* Wv  = W + o; o += (size_t)PD * HID;
    float* bk  = W + o; o += HID;
    float* bv  = W + o; o += HID;
    float* qb_ = W + o; o += (size_t)BB * HORQ * HID;
    float* F1  = W + o; o += (size_t)BB * HORQ * HID;
    float* F2  = W + o; o += (size_t)BB * HORQ * PD;
    float* dl  = W + o; o += (size_t)BB * HORQ * 2;
    float* ob  = W + o; o += (size_t)BB * HORQ * HID;
    float* pm  = W + o; o += 512 * 8;
    float* pl  = W + o; o += 512 * 8;
    float* po  = W + o; o += (size_t)512 * 8 * DH;
    float* kb  = W + o; o += (size_t)BB * NN * HID;
    float* vbuf= W + o; o += (size_t)BB * NN * HID;
    float* P1  = W + o; o += (size_t)BB * NN * HID;
    float* P2  = W + o; o += (size_t)BB * NN * PD;
    // bf16 fragment-packed weights (aligned: o is a multiple of 4 floats here)
    short* Sf = (short*)(W + o);
    short* Wfrag  = Sf;                 // 56*4*64*8 = 114688
    short* w1frag = Sf + 114688;        // 8*2*64*8  = 8192
    short* w2frag = Sf + 114688 + 8192; // 8*4*64*8  = 16384

    float* out0 = (float*)d_out;
    float* out1 = out0 + BB * HORQ * 2;
    float* out2 = out1 + (size_t)BB * NN * HORQ * 2;
    float* out3 = out2 + (size_t)BB * NN * HORQ;

    k_fuse<<<PD + 1, 256, 0, stream>>>(qw, qbias, ipw, ipb, Wk, Wv, bk, bv);
    k_prep<<<72, 256, 0, stream>>>(Wk, Wv, rw1, vw1, ew1, ew2, Wfrag, w1frag, w2frag);
    k_main<<<BB * NN / 64, 256, 0, stream>>>(obs, vis, rel, lnw, lnb, eb1, eb2,
                                             Wfrag, w1frag, w2frag, bk, bv, rw1,
                                             kb, vbuf, P1, P2);
    k_tq<<<BB * HORQ, 256, 0, stream>>>(aobs, avel, te, aw, ab, ipw, ipb, qb_);
    k_att<<<BB * NHD * NC, 256, 0, stream>>>(qb_, kb, vbuf, pm, pl, po);
    k_attc<<<BB * NHD, 256, 0, stream>>>(pm, pl, po, ob);
    k_fut<<<BB * HORQ, 256, 0, stream>>>(ob, opw, opb, rw1, rb1, vw1, vb1, shw, shb, ahw, ahb,
                                         F1, F2, dl, out3);
    k_cum<<<1, 64, 0, stream>>>(aobs, dl, out0);
    k_fin<<<BB * NN / 4, 256, 0, stream>>>(F1, F2, P1, P2, rw2, rb2, vw2, vb2, out0, out1, out2);
}

// Round 3
// 289.961 us; speedup vs baseline: 1.9609x; 1.2076x over previous
//
#include <hip/hip_runtime.h>
#include <math.h>

#define BB 8
#define NN 4096
#define TT 8
#define HORQ 8
#define PD 128
#define HID 256
#define NHD 8
#define DH 32
#define FE 56
#define NC 8
#define CH 512

typedef __attribute__((ext_vector_type(8))) short short8;
typedef __attribute__((ext_vector_type(4))) float floatx4;

// fast gelu: tanh-form, exp-based. max abs err vs exact erf-gelu ~1e-3.
// gelu(x) = x - x/(1+e^{2y}), y = 0.79788456*(x + 0.044715 x^3)
__device__ __forceinline__ float gelu_fast(float x) {
    float x2 = x * x;
    float y2 = x * fmaf(0.0713551f, x2, 1.5957691f);
    float e = __expf(y2);
    return x - x * __builtin_amdgcn_rcpf(1.f + e);
}

// fp32 -> bf16 round-to-nearest-even
__device__ __forceinline__ short f2b(float x) {
    union { float f; unsigned u; } c; c.f = x;
    unsigned r = c.u + 0x7fffu + ((c.u >> 16) & 1u);
    return (short)(r >> 16);
}

// ---------------- fuse query_w into k/v projections (fp32) ----------------
__global__ __launch_bounds__(256) void k_fuse(
    const float* __restrict__ qw, const float* __restrict__ qb,
    const float* __restrict__ ipw, const float* __restrict__ ipb,
    float* __restrict__ Wk, float* __restrict__ Wv,
    float* __restrict__ bk, float* __restrict__ bv)
{
    int j = threadIdx.x;
    int blk = blockIdx.x;
    if (blk < PD) {
        float sk = 0.f, sv = 0.f;
        for (int l = 0; l < HID; l++) {
            float w = qw[blk * HID + l];
            sk += w * ipw[l * 768 + 256 + j];
            sv += w * ipw[l * 768 + 512 + j];
        }
        Wk[blk * HID + j] = sk;
        Wv[blk * HID + j] = sv;
    } else {
        float sk = ipb[256 + j], sv = ipb[512 + j];
        for (int l = 0; l < HID; l++) {
            float w = qb[l];
            sk += w * ipw[l * 768 + 256 + j];
            sv += w * ipw[l * 768 + 512 + j];
        }
        bk[j] = sk;
        bv[j] = sv;
    }
}

// ---------------- pack weights into bf16 MFMA B-fragment layout ----------------
__global__ __launch_bounds__(256) void k_prep(
    const float* __restrict__ Wk, const float* __restrict__ Wv,
    const float* __restrict__ rw1, const float* __restrict__ vw1,
    const float* __restrict__ w1, const float* __restrict__ w2,
    short* __restrict__ Wfrag, short* __restrict__ w1frag, short* __restrict__ w2frag)
{
    int tid = threadIdx.x;
    int blk = blockIdx.x;
    int ks = tid >> 6, lane = tid & 63;
    int quad = lane >> 4, c16 = lane & 15;
    if (blk < 56) {
        int nt = blk;
        int n = nt * 16 + c16;
        for (int j = 0; j < 8; j++) {
            int k = ks * 32 + quad * 8 + j;
            float v;
            if (n < 256)      v = Wk[k * HID + n];
            else if (n < 512) v = Wv[k * HID + (n - 256)];
            else if (n < 768) v = rw1[(256 + k) * HID + (n - 512)];
            else              v = vw1[(256 + k) * PD + (n - 768)];
            Wfrag[((nt * 4 + ks) * 64 + lane) * 8 + j] = f2b(v);
        }
    } else if (blk < 64) {
        if (ks < 2) {
            int nt = blk - 56;
            int n = nt * 16 + c16;
            for (int j = 0; j < 8; j++) {
                int k = ks * 32 + quad * 8 + j;
                float v = (k < FE) ? w1[k * PD + n] : 0.f;
                w1frag[((nt * 2 + ks) * 64 + lane) * 8 + j] = f2b(v);
            }
        }
    } else {
        int nt = blk - 64;
        int n = nt * 16 + c16;
        for (int j = 0; j < 8; j++) {
            int k = ks * 32 + quad * 8 + j;
            w2frag[((nt * 4 + ks) * 64 + lane) * 8 + j] = f2b(w2[k * PD + n]);
        }
    }
}

// ---------------- fused encoder + projections via bf16 MFMA ----------------
#define U1_OFF 0
#define XNB_OFF 17408
#define PTB_OFF 26624
#define RXY_OFF 44032
#define MU_OFF 44544
#define RS_OFF 44800
#define SMEM_BYTES 45056

__global__ __launch_bounds__(256) void k_main(
    const float* __restrict__ obs, const int* __restrict__ vis,
    const float* __restrict__ rel,
    const float* __restrict__ lnw, const float* __restrict__ lnb,
    const float* __restrict__ b1, const float* __restrict__ b2,
    const short* __restrict__ Wfrag, const short* __restrict__ w1frag,
    const short* __restrict__ w2frag,
    const float* __restrict__ bk, const float* __restrict__ bv,
    const float* __restrict__ rw1,
    float* __restrict__ kb, float* __restrict__ vb,
    float* __restrict__ P1, float* __restrict__ P2)
{
    __shared__ __align__(16) char smem[SMEM_BYTES];
    float* xnf = (float*)(smem + U1_OFF);       // [64][57]
    short* h1b = (short*)(smem + U1_OFF);       // [64][136]
    short* xnb = (short*)(smem + XNB_OFF);      // [64][72]
    short* ptb = (short*)(smem + PTB_OFF);      // [64][136]
    float* rxyS = (float*)(smem + RXY_OFF);     // [64][2]
    float* muS = (float*)(smem + MU_OFF);       // [64]
    float* rsS = (float*)(smem + RS_OFF);       // [64]

    int tid = threadIdx.x;
    int w = tid >> 6, lane = tid & 63;
    int quad = lane >> 4, c16 = lane & 15;
    int bn0 = blockIdx.x * 64;

    // phase A: build feat (fp32)
    for (int idx = tid; idx < 64 * FE; idx += 256) {
        int p = idx / FE, e = idx - p * FE;
        int t = e / 7, c = e - t * 7;
        int bn = bn0 + p;
        float v;
        if (c < 2)       v = obs[(bn * TT + t) * 2 + c];
        else if (c < 4)  v = (t == 0) ? 0.f : (obs[(bn * TT + t) * 2 + (c - 2)] - obs[(bn * TT + t - 1) * 2 + (c - 2)]);
        else if (c == 4) v = (float)vis[bn * TT + t];
        else             v = rel[bn * 2 + (c - 5)];
        xnf[p * 57 + e] = v;
    }
    if (tid < 128) rxyS[tid] = rel[bn0 * 2 + tid];
    __syncthreads();

    // phase B: LN stats
    if (tid < 64) {
        float s = 0.f, ss = 0.f;
        for (int e = 0; e < FE; e++) { float v = xnf[tid * 57 + e]; s += v; ss += v * v; }
        float mu = s * (1.f / FE);
        float var = ss * (1.f / FE) - mu * mu;
        muS[tid] = mu;
        rsS[tid] = rsqrtf(var + 1e-5f);
    }
    __syncthreads();

    // phase C: normalize -> bf16 A-layout
    for (int idx = tid; idx < 64 * 64; idx += 256) {
        int p = idx >> 6, e = idx & 63;
        float v = 0.f;
        if (e < FE) v = (xnf[p * 57 + e] - muS[p]) * rsS[p] * lnw[e] + lnb[e];
        xnb[p * 72 + e] = f2b(v);
    }
    __syncthreads();

    // phase D: enc1
    {
        short8 af1[4][2];
        #pragma unroll
        for (int mt = 0; mt < 4; mt++)
            #pragma unroll
            for (int ks = 0; ks < 2; ks++)
                af1[mt][ks] = *(const short8*)(xnb + (mt * 16 + c16) * 72 + ks * 32 + quad * 8);
        #pragma unroll
        for (int ntl = 0; ntl < 2; ntl++) {
            int nt = w * 2 + ntl;
            short8 bf1[2];
            #pragma unroll
            for (int ks = 0; ks < 2; ks++)
                bf1[ks] = *(const short8*)(w1frag + ((nt * 2 + ks) * 64 + lane) * 8);
            int col = nt * 16 + c16;
            float bb = b1[col];
            #pragma unroll
            for (int mt = 0; mt < 4; mt++) {
                floatx4 acc = {0.f, 0.f, 0.f, 0.f};
                acc = __builtin_amdgcn_mfma_f32_16x16x32_bf16(af1[mt][0], bf1[0], acc, 0, 0, 0);
                acc = __builtin_amdgcn_mfma_f32_16x16x32_bf16(af1[mt][1], bf1[1], acc, 0, 0, 0);
                #pragma unroll
                for (int r = 0; r < 4; r++) {
                    int row = mt * 16 + quad * 4 + r;
                    h1b[row * 136 + col] = f2b(gelu_fast(acc[r] + bb));
                }
            }
        }
    }
    __syncthreads();

    // phase E: enc2
    {
        short8 af2[4][4];
        #pragma unroll
        for (int mt = 0; mt < 4; mt++)
            #pragma unroll
            for (int ks = 0; ks < 4; ks++)
                af2[mt][ks] = *(const short8*)(h1b + (mt * 16 + c16) * 136 + ks * 32 + quad * 8);
        #pragma unroll
        for (int ntl = 0; ntl < 2; ntl++) {
            int nt = w * 2 + ntl;
            short8 bf2[4];
            #pragma unroll
            for (int ks = 0; ks < 4; ks++)
                bf2[ks] = *(const short8*)(w2frag + ((nt * 4 + ks) * 64 + lane) * 8);
            int col = nt * 16 + c16;
            float bb = b2[col];
            #pragma unroll
            for (int mt = 0; mt < 4; mt++) {
                floatx4 acc = {0.f, 0.f, 0.f, 0.f};
                #pragma unroll
                for (int ks = 0; ks < 4; ks++)
                    acc = __builtin_amdgcn_mfma_f32_16x16x32_bf16(af2[mt][ks], bf2[ks], acc, 0, 0, 0);
                #pragma unroll
                for (int r = 0; r < 4; r++) {
                    int row = mt * 16 + quad * 4 + r;
                    ptb[row * 136 + col] = f2b(gelu_fast(acc[r] + bb));
                }
            }
        }
    }
    __syncthreads();

    // phase F: big GEMM [64x128] @ [128x896]
    {
        short8 af[4][4];
        #pragma unroll
        for (int mt = 0; mt < 4; mt++)
            #pragma unroll
            for (int ks = 0; ks < 4; ks++)
                af[mt][ks] = *(const short8*)(ptb + (mt * 16 + c16) * 136 + ks * 32 + quad * 8);
        for (int i = 0; i < 14; i++) {
            int nt = w + i * 4;
            short8 bf[4];
            #pragma unroll
            for (int ks = 0; ks < 4; ks++)
                bf[ks] = *(const short8*)(Wfrag + ((nt * 4 + ks) * 64 + lane) * 8);
            floatx4 acc[4];
            #pragma unroll
            for (int mt = 0; mt < 4; mt++) {
                acc[mt] = (floatx4){0.f, 0.f, 0.f, 0.f};
                #pragma unroll
                for (int ks = 0; ks < 4; ks++)
                    acc[mt] = __builtin_amdgcn_mfma_f32_16x16x32_bf16(af[mt][ks], bf[ks], acc[mt], 0, 0, 0);
            }
            int n = nt * 16 + c16;
            if (nt < 16) {
                float bb = bk[n];
                #pragma unroll
                for (int mt = 0; mt < 4; mt++)
                    #pragma unroll
                    for (int r = 0; r < 4; r++) {
                        int row = mt * 16 + quad * 4 + r;
                        kb[(size_t)(bn0 + row) * HID + n] = acc[mt][r] + bb;
                    }
            } else if (nt < 32) {
                int j = n - 256;
                float bb = bv[j];
                #pragma unroll
                for (int mt = 0; mt < 4; mt++)
                    #pragma unroll
                    for (int r = 0; r < 4; r++) {
                        int row = mt * 16 + quad * 4 + r;
                        vb[(size_t)(bn0 + row) * HID + j] = acc[mt][r] + bb;
                    }
            } else if (nt < 48) {
                int j = n - 512;
                float wr0 = rw1[384 * HID + j], wr1 = rw1[385 * HID + j];
                #pragma unroll
                for (int mt = 0; mt < 4; mt++)
                    #pragma unroll
                    for (int r = 0; r < 4; r++) {
                        int row = mt * 16 + quad * 4 + r;
                        P1[(size_t)(bn0 + row) * HID + j] =
                            acc[mt][r] + rxyS[row * 2] * wr0 + rxyS[row * 2 + 1] * wr1;
                    }
            } else {
                int j = n - 768;
                #pragma unroll
                for (int mt = 0; mt < 4; mt++)
                    #pragma unroll
                    for (int r = 0; r < 4; r++) {
                        int row = mt * 16 + quad * 4 + r;
                        P2[(size_t)(bn0 + row) * PD + j] = acc[mt][r];
                    }
            }
        }
    }
}

// ---------------- tq and q ----------------
__global__ __launch_bounds__(256) void k_tq(
    const float* __restrict__ aobs, const float* __restrict__ avel,
    const float* __restrict__ te, const float* __restrict__ aw, const float* __restrict__ ab,
    const float* __restrict__ ipw, const float* __restrict__ ipb,
    float* __restrict__ qb_)
{
    __shared__ float af[32];
    __shared__ float tq[HID];
    int tid = threadIdx.x;
    int b = blockIdx.x >> 3, h = blockIdx.x & 7;
    if (tid < 32) {
        int t = tid >> 2, m = tid & 3;
        af[tid] = (m < 2) ? aobs[(b * TT + t) * 2 + m] : avel[(b * TT + t) * 2 + (m - 2)];
    }
    __syncthreads();
    float s = te[h * HID + tid] + ab[tid];
    for (int i = 0; i < 32; i++) s += af[i] * aw[i * HID + tid];
    tq[tid] = s;
    __syncthreads();
    float qv = ipb[tid];
    for (int i = 0; i < HID; i++) qv += tq[i] * ipw[i * 768 + tid];
    qb_[(size_t)blockIdx.x * HID + tid] = qv;
}

// ---------------- attention: partial (per b,head,chunk) ----------------
// O-phase: 8 groups of 32 lanes; group g covers 64 nn rows, V read ONCE,
// 8 qq accumulators in registers, partial-sum combine via LDS.
__global__ __launch_bounds__(256) void k_att(
    const float* __restrict__ qbuf, const float* __restrict__ kb, const float* __restrict__ vbuf,
    float* __restrict__ pm, float* __restrict__ pl, float* __restrict__ po)
{
    __shared__ float qs[8][DH];       // 1 KB
    __shared__ float sc[8][CH];       // 16 KB
    __shared__ float pos[8][8][DH];   // 8 KB [group][qq][d]
    int tid = threadIdx.x;
    int bidx = blockIdx.x;
    int c = bidx & (NC - 1);
    int head = (bidx >> 3) & 7;
    int b = bidx >> 6;
    qs[tid >> 5][tid & 31] = qbuf[(size_t)(b * HORQ + (tid >> 5)) * HID + head * DH + (tid & 31)];
    __syncthreads();
    const float scale = 0.17677669529663688110f; // 1/sqrt(32)
    for (int nn = tid; nn < CH; nn += 256) {
        int n = c * CH + nn;
        const float* kp = kb + (size_t)(b * NN + n) * HID + head * DH;
        float kr[DH];
        #pragma unroll
        for (int u = 0; u < DH; u += 4) {
            float4 f = *reinterpret_cast<const float4*>(kp + u);
            kr[u] = f.x; kr[u + 1] = f.y; kr[u + 2] = f.z; kr[u + 3] = f.w;
        }
        #pragma unroll
        for (int qq = 0; qq < 8; qq++) {
            float s = 0.f;
            #pragma unroll
            for (int d = 0; d < DH; d++) s += qs[qq][d] * kr[d];
            sc[qq][nn] = s * scale;
        }
    }
    __syncthreads();
    int qq = tid >> 5, r = tid & 31;
    float mx = -1e30f;
    for (int nn = r; nn < CH; nn += 32) mx = fmaxf(mx, sc[qq][nn]);
    #pragma unroll
    for (int m = 16; m; m >>= 1) mx = fmaxf(mx, __shfl_xor(mx, m, 32));
    float sum = 0.f;
    for (int nn = r; nn < CH; nn += 32) { float e = __expf(sc[qq][nn] - mx); sc[qq][nn] = e; sum += e; }
    #pragma unroll
    for (int m = 16; m; m >>= 1) sum += __shfl_xor(sum, m, 32);
    if (r == 0) { pm[bidx * 8 + qq] = mx; pl[bidx * 8 + qq] = sum; }
    __syncthreads();
    // O partial: group g handles nn in [g*64, g*64+64)
    {
        int g = tid >> 5, d = tid & 31;
        float oacc[8];
        #pragma unroll
        for (int q2 = 0; q2 < 8; q2++) oacc[q2] = 0.f;
        const float* vp = vbuf + ((size_t)(b * NN + c * CH + g * 64)) * HID + head * DH + d;
        for (int i = 0; i < 64; i++) {
            float v = vp[(size_t)i * HID];
            int nn = g * 64 + i;
            #pragma unroll
            for (int q2 = 0; q2 < 8; q2++) oacc[q2] += sc[q2][nn] * v;
        }
        #pragma unroll
        for (int q2 = 0; q2 < 8; q2++) pos[g][q2][d] = oacc[q2];
    }
    __syncthreads();
    {
        int q2 = tid >> 5, d = tid & 31;
        float o = 0.f;
        #pragma unroll
        for (int gg = 0; gg < 8; gg++) o += pos[gg][q2][d];
        po[(size_t)(bidx * 8 + q2) * DH + d] = o;
    }
}

// ---------------- attention: combine chunks ----------------
__global__ __launch_bounds__(256) void k_attc(
    const float* __restrict__ pm, const float* __restrict__ pl, const float* __restrict__ po,
    float* __restrict__ ob)
{
    int tid = threadIdx.x;
    int bh = blockIdx.x; // b*8+head
    int b = bh >> 3, head = bh & 7;
    int qq = tid >> 5, d = tid & 31;
    float M = -1e30f;
    for (int c = 0; c < NC; c++) M = fmaxf(M, pm[(bh * NC + c) * 8 + qq]);
    float L = 0.f, o = 0.f;
    for (int c = 0; c < NC; c++) {
        float w = __expf(pm[(bh * NC + c) * 8 + qq] - M);
        L += w * pl[(bh * NC + c) * 8 + qq];
        o += w * po[(size_t)((bh * NC + c) * 8 + qq) * DH + d];
    }
    ob[(size_t)(b * HORQ + qq) * HID + head * DH + d] = o / L;
}

// ---------------- future + all (b,h)-row heads ----------------
__global__ __launch_bounds__(256) void k_fut(
    const float* __restrict__ ob, const float* __restrict__ opw, const float* __restrict__ opb,
    const float* __restrict__ rw1, const float* __restrict__ rb1,
    const float* __restrict__ vw1, const float* __restrict__ vb1,
    const float* __restrict__ shw, const float* __restrict__ shb,
    const float* __restrict__ ahw, const float* __restrict__ ahb,
    float* __restrict__ F1, float* __restrict__ F2, float* __restrict__ dl, float* __restrict__ sem)
{
    __shared__ float orow[HID], fut[HID];
    int tid = threadIdx.x;
    int bh = blockIdx.x;
    orow[tid] = ob[(size_t)bh * HID + tid];
    __syncthreads();
    float s = opb[tid];
    for (int i = 0; i < HID; i++) s += orow[i] * opw[i * HID + tid];
    fut[tid] = s;
    __syncthreads();
    float f1 = rb1[tid];
    for (int i = 0; i < HID; i++) f1 += fut[i] * rw1[i * HID + tid];
    F1[(size_t)bh * HID + tid] = f1;
    if (tid < PD) {
        float f2 = vb1[tid];
        for (int i = 0; i < HID; i++) f2 += fut[i] * vw1[i * PD + tid];
        F2[(size_t)bh * PD + tid] = f2;
    }
    if (tid < 32) {
        float s3 = shb[tid];
        for (int i = 0; i < HID; i++) s3 += fut[i] * shw[i * 32 + tid];
        sem[bh * 32 + tid] = s3;
    }
    if (tid < 2) {
        float a = ahb[tid];
        for (int i = 0; i < HID; i++) a += fut[i] * ahw[i * 2 + tid];
        dl[bh * 2 + tid] = 0.1f * tanhf(a);
    }
}

// ---------------- anchor cumsum ----------------
__global__ void k_cum(const float* __restrict__ aobs, const float* __restrict__ dl, float* __restrict__ out0)
{
    int tid = threadIdx.x;
    if (tid < 16) {
        int b = tid >> 1, c = tid & 1;
        float acc = aobs[(b * TT + 7) * 2 + c];
        for (int h = 0; h < HORQ; h++) {
            acc += dl[(b * HORQ + h) * 2 + c];
            out0[(b * HORQ + h) * 2 + c] = acc;
        }
    }
}

// ---------------- final epilogue: pred_points + vis_logits ----------------
// 2 points per wave (32 lanes each); fast gelu; 5-level butterfly reduce.
__global__ __launch_bounds__(256) void k_fin(
    const float* __restrict__ F1, const float* __restrict__ F2,
    const float* __restrict__ P1, const float* __restrict__ P2,
    const float* __restrict__ rw2, const float* __restrict__ rb2,
    const float* __restrict__ vw2, const float* __restrict__ vb2,
    const float* __restrict__ ap,
    float* __restrict__ out1, float* __restrict__ out2)
{
    int tid = threadIdx.x;
    int wv = tid >> 6;
    int half = (tid >> 5) & 1;
    int l = tid & 31;
    size_t bn = (size_t)blockIdx.x * 8 + wv * 2 + half;
    int b = (int)(bn >> 12);
    float p1r[8], w20[8], w21[8];
    #pragma unroll
    for (int u = 0; u < 8; u++) {
        int j = l + 32 * u;
        p1r[u] = P1[bn * HID + j];
        w20[u] = rw2[j * 2];
        w21[u] = rw2[j * 2 + 1];
    }
    float p2r[4], wv2r[4];
    #pragma unroll
    for (int u = 0; u < 4; u++) {
        int j = l + 32 * u;
        p2r[u] = P2[bn * PD + j];
        wv2r[u] = vw2[j];
    }
    float rb20 = rb2[0], rb21 = rb2[1], vb20 = vb2[0];
    for (int h = 0; h < HORQ; h++) {
        const float* f1p = F1 + (size_t)(b * HORQ + h) * HID;
        const float* f2p = F2 + (size_t)(b * HORQ + h) * PD;
        float s0 = 0.f, s1 = 0.f, sv = 0.f;
        #pragma unroll
        for (int u = 0; u < 8; u++) {
            float g = gelu_fast(f1p[l + 32 * u] + p1r[u]);
            s0 += g * w20[u];
            s1 += g * w21[u];
        }
        #pragma unroll
        for (int u = 0; u < 4; u++) {
            float g = gelu_fast(f2p[l + 32 * u] + p2r[u]);
            sv += g * wv2r[u];
        }
        #pragma unroll
        for (int m = 16; m; m >>= 1) {
            s0 += __shfl_xor(s0, m);
            s1 += __shfl_xor(s1, m);
            sv += __shfl_xor(sv, m);
        }
        if (l == 0) {
            float rx = 0.1f * tanhf(s0 + rb20);
            float ry = 0.1f * tanhf(s1 + rb21);
            out1[(bn * HORQ + h) * 2 + 0] = ap[(b * HORQ + h) * 2 + 0] + rx;
            out1[(bn * HORQ + h) * 2 + 1] = ap[(b * HORQ + h) * 2 + 1] + ry;
            out2[bn * HORQ + h] = sv + vb20;
        }
    }
}

extern "C" void kernel_launch(void* const* d_in, const int* in_sizes, int n_in,
                              void* d_out, int out_size, void* d_ws, size_t ws_size,
                              hipStream_t stream)
{
    const float* obs  = (const float*)d_in[0];
    const int*   vis  = (const int*)d_in[1];
    const float* rel  = (const float*)d_in[2];
    const float* aobs = (const float*)d_in[3];
    const float* avel = (const float*)d_in[4];
    const float* lnw = (const float*)d_in[6];
    const float* lnb = (const float*)d_in[7];
    const float* ew1 = (const float*)d_in[8];
    const float* eb1 = (const float*)d_in[9];
    const float* ew2 = (const float*)d_in[10];
    const float* eb2 = (const float*)d_in[11];
    const float* te  = (const float*)d_in[12];
    const float* aw  = (const float*)d_in[13];
    const float* ab  = (const float*)d_in[14];
    const float* qw  = (const float*)d_in[15];
    const float* qbias = (const float*)d_in[16];
    const float* ipw = (const float*)d_in[17];
    const float* ipb = (const float*)d_in[18];
    const float* opw = (const float*)d_in[19];
    const float* opb = (const float*)d_in[20];
    const float* ahw = (const float*)d_in[21];
    const float* ahb = (const float*)d_in[22];
    const float* rw1 = (const float*)d_in[23];
    const float* rb1 = (const float*)d_in[24];
    const float* rw2 = (const float*)d_in[25];
    const float* rb2 = (const float*)d_in[26];
    const float* vw1 = (const float*)d_in[27];
    const float* vb1 = (const float*)d_in[28];
    const float* vw2 = (const float*)d_in[29];
    const float* vb2 = (const float*)d_in[30];
    const float* shw = (const float*)d_in[31];
    const float* shb = (const float*)d_in[32];

    float* W = (float*)d_ws;
    size_t o = 0;
    float* Wk  = W + o; o += (size_t)PD * HID;
    float* Wv  = W + o; o += (size_t)PD * HID;
    float* bk  = W + o; o += HID;
    float* bv  = W + o; o += HID;
    float* qb_ = W + o; o += (size_t)BB * HORQ * HID;
    float* F1  = W + o; o += (size_t)BB * HORQ * HID;
    float* F2  = W + o; o += (size_t)BB * HORQ * PD;
    float* dl  = W + o; o += (size_t)BB * HORQ * 2;
    float* ob  = W + o; o += (size_t)BB * HORQ * HID;
    float* pm  = W + o; o += 512 * 8;
    float* pl  = W + o; o += 512 * 8;
    float* po  = W + o; o += (size_t)512 * 8 * DH;
    float* kb  = W + o; o += (size_t)BB * NN * HID;
    float* vbuf= W + o; o += (size_t)BB * NN * HID;
    float* P1  = W + o; o += (size_t)BB * NN * HID;
    float* P2  = W + o; o += (size_t)BB * NN * PD;
    short* Sf = (short*)(W + o);
    short* Wfrag  = Sf;                 // 56*4*64*8 = 114688
    short* w1frag = Sf + 114688;        // 8*2*64*8  = 8192
    short* w2frag = Sf + 114688 + 8192; // 8*4*64*8  = 16384

    float* out0 = (float*)d_out;
    float* out1 = out0 + BB * HORQ * 2;
    float* out2 = out1 + (size_t)BB * NN * HORQ * 2;
    float* out3 = out2 + (size_t)BB * NN * HORQ;

    k_fuse<<<PD + 1, 256, 0, stream>>>(qw, qbias, ipw, ipb, Wk, Wv, bk, bv);
    k_prep<<<72, 256, 0, stream>>>(Wk, Wv, rw1, vw1, ew1, ew2, Wfrag, w1frag, w2frag);
    k_main<<<BB * NN / 64, 256, 0, stream>>>(obs, vis, rel, lnw, lnb, eb1, eb2,
                                             Wfrag, w1frag, w2frag, bk, bv, rw1,
                                             kb, vbuf, P1, P2);
    k_tq<<<BB * HORQ, 256, 0, stream>>>(aobs, avel, te, aw, ab, ipw, ipb, qb_);
    k_att<<<BB * NHD * NC, 256, 0, stream>>>(qb_, kb, vbuf, pm, pl, po);
    k_attc<<<BB * NHD, 256, 0, stream>>>(pm, pl, po, ob);
    k_fut<<<BB * HORQ, 256, 0, stream>>>(ob, opw, opb, rw1, rb1, vw1, vb1, shw, shb, ahw, ahb,
                                         F1, F2, dl, out3);
    k_cum<<<1, 64, 0, stream>>>(aobs, dl, out0);
    k_fin<<<BB * NN / 8, 256, 0, stream>>>(F1, F2, P1, P2, rw2, rb2, vw2, vb2, out0, out1, out2);
}